// Round 1
// baseline (1277.443 us; speedup 1.0000x reference)
//
#include <hip/hip_runtime.h>
#include <math.h>

#define BATCH 32
#define NN 1024
#define MM 1024
#define WORDS_PER_ROW 64   // 1024 cols * 2 bits / 32 bits
#define LDIAG (NN + MM - 1) // 2047

__global__ void zero_out_kernel(float* out) { out[0] = 0.0f; }

// One block per batch. threadIdx.x = row i in [0, NN).
// Phase 1: wavefront DP over anti-diagonals, storing 2-bit backtrack
//          decisions (0=diag,1=up,2=left; JAX argmin tie order) packed into ws.
// Phase 2: thread 0 backtracks and accumulates the L1 loss along the path.
__global__ __launch_bounds__(1024) void dtw_kernel(
    const float* __restrict__ preds,    // [B, NN, 4]
    const float* __restrict__ targs,    // [B, MM, 4]
    const float* __restrict__ subcoef,  // [2]
    unsigned* __restrict__ dec,         // [B, NN, WORDS_PER_ROW]
    float* __restrict__ out)
{
    const int b   = blockIdx.x;
    const int tid = threadIdx.x;           // row index i

    __shared__ float px[NN], py[NN];       // pred features 0,1
    __shared__ float tx[MM], ty[MM];       // targ features 0,1
    __shared__ float diag[3][NN];          // rotating anti-diagonal buffers

    const float INF = __builtin_inff();

    // Stage coords (features 0,1 of each 4-float row) via float4 loads.
    {
        const float4 p4 = ((const float4*)preds)[(size_t)b * NN + tid];
        px[tid] = p4.x; py[tid] = p4.y;
        const float4 t4 = ((const float4*)targs)[(size_t)b * MM + tid];
        tx[tid] = t4.x; ty[tid] = t4.y;
        diag[0][tid] = INF; diag[1][tid] = INF; diag[2][tid] = INF;
    }
    __syncthreads();

    const float pxi = px[tid];
    const float pyi = py[tid];
    unsigned* decRow = dec + ((size_t)b * NN + tid) * WORDS_PER_ROW;
    unsigned packed = 0;

    for (int k = 0; k < LDIAG; ++k) {
        const int cur = k % 3;
        const int p1  = (k + 2) % 3;   // diagonal k-1
        const int p2  = (k + 1) % 3;   // diagonal k-2
        const int j   = k - tid;
        float res = INF;
        if (j >= 0 && j < MM) {
            const float dx = pxi - tx[j];
            const float dy = pyi - ty[j];
            const float c  = sqrtf(dx * dx + dy * dy);
            const float up = (tid > 0) ? diag[p1][tid - 1] : INF;  // D[i-1, j]
            const float dg = (tid > 0) ? diag[p2][tid - 1] : INF;  // D[i-1, j-1]
            const float lf = diag[p1][tid];                        // D[i,   j-1]
            float best = fminf(fminf(up, dg), lf);
            // argmin over [dg, up, lf], first-minimum tie order (JAX argmin)
            unsigned m;
            if (dg <= up && dg <= lf)      m = 0u;
            else if (up <= lf)             m = 1u;
            else                           m = 2u;
            packed |= m << ((j & 15) * 2);
            if ((j & 15) == 15) { decRow[j >> 4] = packed; packed = 0u; }
            if (!(best < INF)) best = 0.0f;   // seeds D[0,0] = cost[0,0]
            res = c + best;
        }
        diag[cur][tid] = res;
        __syncthreads();
    }

    // ---- Phase 2: sequential backtrack by thread 0 ----
    if (tid == 0) {
        const float sc0 = subcoef[0];
        const float sc1 = subcoef[1];
        const unsigned* decB = dec + (size_t)b * NN * WORDS_PER_ROW;
        int i = NN - 1, j = MM - 1;
        float loss = 0.0f;
        while (true) {
            loss += fabsf(px[i] - tx[j]) * sc0 + fabsf(py[i] - ty[j]) * sc1;
            if (i == 0 && j == 0) break;
            const unsigned w = decB[(size_t)i * WORDS_PER_ROW + (j >> 4)];
            const unsigned m = (w >> ((j & 15) * 2)) & 3u;
            if (m == 0u)      { --i; --j; }
            else if (m == 1u) { --i; }
            else              { --j; }
        }
        atomicAdd(out, loss);
    }
}

extern "C" void kernel_launch(void* const* d_in, const int* in_sizes, int n_in,
                              void* d_out, int out_size, void* d_ws, size_t ws_size,
                              hipStream_t stream) {
    const float* preds   = (const float*)d_in[0];
    const float* targs   = (const float*)d_in[1];
    const float* subcoef = (const float*)d_in[2];
    float* out = (float*)d_out;
    unsigned* dec = (unsigned*)d_ws;   // needs 32*1024*64*4 = 8 MB

    zero_out_kernel<<<1, 1, 0, stream>>>(out);
    dtw_kernel<<<BATCH, NN, 0, stream>>>(preds, targs, subcoef, dec, out);
}

// Round 2
// 839.127 us; speedup vs baseline: 1.5223x; 1.5223x over previous
//
#include <hip/hip_runtime.h>
#include <math.h>

#define BATCH 32
#define NN 1024
#define MM 1024
#define TT 256                 // threads per block (4 waves -> 4 SIMDs)
#define RR 4                   // rows per thread
#define STEPS (MM + TT - 1)    // 1279 skewed wavefront steps
#define TPB (MM / 4)           // tile columns per batch (256)
#define TILE_WORDS_PER_BATCH ((NN / 4) * (MM / 4))   // 64K words = 256KB

__global__ void zero_out_kernel(float* out) { out[0] = 0.0f; }

// One block per batch. Thread t owns rows [4t, 4t+4). Skewed column sweep:
// at step s, thread t processes column j = s - t over its 4 rows.
// Boundary D[4t-1][j] flows from thread t-1 via double-buffered LDS (1 barrier/step).
// Decisions (2-bit, JAX argmin([dg,up,lf]) first-min order) are packed into
// 4x4-tile uint32 words for cache/prefetch-friendly backtrack.
__global__ __launch_bounds__(TT) void dtw_kernel(
    const float* __restrict__ preds,    // [B, NN, 4]
    const float* __restrict__ targs,    // [B, MM, 4]
    const float* __restrict__ subcoef,  // [2]
    unsigned* __restrict__ dec,         // [B, NN/4, MM/4] tile words
    float* __restrict__ out)
{
    const int b = blockIdx.x;
    const int t = threadIdx.x;
    const float INF = __builtin_inff();

    __shared__ float pxA[NN], pyA[NN];   // pred coords (also used by backtrack)
    __shared__ float txy[2 * MM];        // interleaved targ coords
    __shared__ float bbuf[2][TT];        // band-boundary D values, double buffered

    // Coalesced staging of features 0,1.
    for (int it = 0; it < NN / TT; ++it) {
        const int idx = it * TT + t;
        const float4 p4 = ((const float4*)preds)[(size_t)b * NN + idx];
        pxA[idx] = p4.x; pyA[idx] = p4.y;
        const float4 t4 = ((const float4*)targs)[(size_t)b * MM + idx];
        txy[2 * idx] = t4.x; txy[2 * idx + 1] = t4.y;
    }
    bbuf[0][t] = INF;
    bbuf[1][t] = INF;
    __syncthreads();

    float pxr[RR], pyr[RR], Dp[RR];
    #pragma unroll
    for (int r = 0; r < RR; ++r) {
        pxr[r] = pxA[RR * t + r];
        pyr[r] = pyA[RR * t + r];
        Dp[r]  = INF;                    // D[row][j-1] before column 0
    }

    // dg boundary for row 4t at the current column. For thread 0 this is
    // D[-1][j-1]: INF everywhere except the (0,0) seed, where feeding 0
    // reproduces the reference's inf->0 substitution exactly (argmin=0 too).
    float dgB = (t == 0) ? 0.0f : INF;
    unsigned packed = 0;
    unsigned* decB = dec + (size_t)b * TILE_WORDS_PER_BATCH;

    for (int s = 0; s < STEPS; ++s) {
        const int j = s - t;
        const float upB = (t == 0) ? INF : bbuf[(s + 1) & 1][t - 1]; // D[4t-1][j]
        if (j >= 0 && j < MM) {
            const float txj = txy[2 * j], tyj = txy[2 * j + 1];
            float up = upB;    // D[i-1][j]
            float dg = dgB;    // D[i-1][j-1]
            unsigned mbits = 0;
            float Dc[RR];
            #pragma unroll
            for (int r = 0; r < RR; ++r) {
                const float dx = pxr[r] - txj;
                const float dy = pyr[r] - tyj;
                const float c  = sqrtf(dx * dx + dy * dy);
                const float lf = Dp[r];                     // D[i][j-1]
                // JAX argmin over [dg, up, lf], first-minimum tie order.
                const unsigned m = (dg <= up && dg <= lf) ? 0u
                                 : ((up <= lf) ? 1u : 2u);
                mbits |= m << (r * 8 + (j & 3) * 2);
                const float best = fminf(up, fminf(dg, lf));
                Dc[r] = c + best;
                dg = lf;       // next row's D[i-1][j-1]
                up = Dc[r];    // next row's D[i-1][j]
            }
            #pragma unroll
            for (int r = 0; r < RR; ++r) Dp[r] = Dc[r];
            packed |= mbits;
            if ((j & 3) == 3) {                 // tile column complete
                decB[(unsigned)t * TPB + (j >> 2)] = packed;
                packed = 0;
            }
            bbuf[s & 1][t] = Dp[RR - 1];        // expose D[4t+3][j] to thread t+1
        }
        dgB = upB;   // this step's up boundary is next step's dg boundary
        __syncthreads();
    }

    __threadfence_block();
    __syncthreads();

    // ---- Backtrack: thread 0, tile-word walk with 3-neighbor prefetch ----
    if (t == 0) {
        const float sc0 = subcoef[0];
        const float sc1 = subcoef[1];
        int i = NN - 1, jj = MM - 1;
        float loss = 0.0f;
        int ti = i >> 2, tj = jj >> 2;
        unsigned w = decB[ti * TPB + tj];
        while (true) {
            // Prefetch the 3 possible next tiles (clamped; unused if not taken).
            const int tjl = (tj > 0) ? tj - 1 : 0;
            const int til = (ti > 0) ? ti - 1 : 0;
            const unsigned wl = decB[ti * TPB + tjl];   // left
            const unsigned wu = decB[til * TPB + tj];   // up
            const unsigned wd = decB[til * TPB + tjl];  // diag
            // In-tile walk (word in register).
            bool done = false;
            while (true) {
                loss += fabsf(pxA[i] - txy[2 * jj])     * sc0
                      + fabsf(pyA[i] - txy[2 * jj + 1]) * sc1;
                if ((i | jj) == 0) { done = true; break; }
                const unsigned m = (w >> (((i & 3) * 4 + (jj & 3)) * 2)) & 3u;
                i  -= (m != 2u);
                jj -= (m != 1u);
                if ((i >> 2) != ti || (jj >> 2) != tj) break;
            }
            if (done) break;
            const int nti = i >> 2, ntj = jj >> 2;
            w = (nti == ti) ? wl : ((ntj == tj) ? wu : wd);
            ti = nti; tj = ntj;
        }
        atomicAdd(out, loss);
    }
}

extern "C" void kernel_launch(void* const* d_in, const int* in_sizes, int n_in,
                              void* d_out, int out_size, void* d_ws, size_t ws_size,
                              hipStream_t stream) {
    const float* preds   = (const float*)d_in[0];
    const float* targs   = (const float*)d_in[1];
    const float* subcoef = (const float*)d_in[2];
    float* out = (float*)d_out;
    unsigned* dec = (unsigned*)d_ws;   // needs 32*64K*4 = 8 MB

    zero_out_kernel<<<1, 1, 0, stream>>>(out);
    dtw_kernel<<<BATCH, TT, 0, stream>>>(preds, targs, subcoef, dec, out);
}